// Round 9
// baseline (170.102 us; speedup 1.0000x reference)
//
#include <hip/hip_runtime.h>

// InformPooling, two-pass scheme, chunk=4 rows with within-superchunk prefix sums.
//   value0 [8,16384,128] r=1.0 ; value1 [8,8192,128] r=0.5 ; value2 [8,4096,256] r=0.25
//   start/duration [8,512]; out [8,512,512] f32 (channels concat 128|128|256).
//
// Wall decomposition (R6/R7): ~81us harness ws re-poison fills (2x256MiB @6.6TB/s,
//   uncontrollable) + launch gaps + prefix (<=40) + gather (~25).
// R8 change: prefix issues 16 loads in flight per batch (was 8) — amortize the
//   reduce/store chain over 2x bytes, double outstanding loads/wave. Target: prefix
//   toward the ~30us stream floor (168MB @ ~5.5-6TB/s).
// NOTE R8 bench: GPUAcquisitionTimeout (infra) — kernel never ran. Resubmission.
// Pass 1 (prefix): nt-load v (keeps LLC clean). Wave owns a superchunk (pools0/1:
//   64 rows = 16 chunks of 4; pool2: 32 rows = 8 chunks), writes inclusive prefix of
//   chunk sums into P. Stores inside the batch loop (R3 spill lesson).
//   P0 [8][4096][128], P1 [8][2048][128], P2 [8][1024][256] = 33.6 MB, temporal.
// Pass 2 (gather): interior [cs,ce) = P[ce-1] - (cs%SCH ? P[cs-1] : 0) + middle SS
//   (SS[m]=P[m*SCH+SCH-1]); edges <=3 rows from v each end.

constexpr int   kB   = 8;
constexpr int   kN   = 512;
constexpr float kEps = 1e-3f;

// float offsets into ws
constexpr size_t P0_OFF = 0;                                 // [8][4096][128]
constexpr size_t P1_OFF = (size_t)8 * 4096 * 128;            // [8][2048][128]
constexpr size_t P2_OFF = P1_OFF + (size_t)8 * 2048 * 128;   // [8][1024][256]

typedef float f32x4 __attribute__((ext_vector_type(4)));

__device__ __forceinline__ float4 ldnt4(const float4* p) {
    f32x4 v = __builtin_nontemporal_load((const f32x4*)p);
    return make_float4(v.x, v.y, v.z, v.w);
}

__device__ __forceinline__ void acc4(float4& a, const float4 x) {
    a.x += x.x; a.y += x.y; a.z += x.z; a.w += x.w;
}
__device__ __forceinline__ void acc4w(float4& a, const float4 x, float w) {
    a.x = fmaf(w, x.x, a.x); a.y = fmaf(w, x.y, a.y);
    a.z = fmaf(w, x.z, a.z); a.w = fmaf(w, x.w, a.w);
}
__device__ __forceinline__ void sub4(float4& a, const float4 x) {
    a.x -= x.x; a.y -= x.y; a.z -= x.z; a.w -= x.w;
}
__device__ __forceinline__ float4 xor32_add(float4 a) {
    a.x += __shfl_xor(a.x, 32);
    a.y += __shfl_xor(a.y, 32);
    a.z += __shfl_xor(a.z, 32);
    a.w += __shfl_xor(a.w, 32);
    return a;
}

// ---------------- pass 1: superchunk prefix sums (chunk = 4 rows) ----------------
// units: pool0 = 2048 (8b x 256 sc of 64 rows), pool1 = 1024 (8b x 128),
//        pool2 = 1024 (8b x 128 sc of 32 rows).  4096 waves total.
__global__ __launch_bounds__(256) void prefix_kernel(
    const float* __restrict__ v0, const float* __restrict__ v1,
    const float* __restrict__ v2, float* __restrict__ ws)
{
    const int w    = (blockIdx.x * 256 + threadIdx.x) >> 6;
    const int lane = threadIdx.x & 63;
    const int hi   = lane >> 5;

    if (w < 3072) {                 // pools 0/1: pair-row layout (lane<32 even row, lane>=32 odd)
        const float* v;  float* Pb;  int T;
        int b, sc;
        if (w < 2048) { b = w >> 8;  sc = w & 255;  v = v0; T = 16384;
                        Pb = ws + P0_OFF + ((size_t)b * 4096 + (size_t)sc * 16) * 128; }
        else { const int idx = w - 2048; b = idx >> 7; sc = idx & 127; v = v1; T = 8192;
               Pb = ws + P1_OFF + ((size_t)b * 2048 + (size_t)sc * 16) * 128; }

        const float4* p = (const float4*)v + ((size_t)b * T + (size_t)sc * 64) * 32 + lane;
        float4 run = make_float4(0.f, 0.f, 0.f, 0.f);
#pragma unroll
        for (int h = 0; h < 2; h++) {           // 32 rows = 8 chunks; 16 pair-loads in flight
            const float4* q = p + (size_t)(16 * h) * 64;
            float4 x0  = ldnt4(&q[ 0 * 64]), x1  = ldnt4(&q[ 1 * 64]);
            float4 x2  = ldnt4(&q[ 2 * 64]), x3  = ldnt4(&q[ 3 * 64]);
            float4 x4  = ldnt4(&q[ 4 * 64]), x5  = ldnt4(&q[ 5 * 64]);
            float4 x6  = ldnt4(&q[ 6 * 64]), x7  = ldnt4(&q[ 7 * 64]);
            float4 x8  = ldnt4(&q[ 8 * 64]), x9  = ldnt4(&q[ 9 * 64]);
            float4 x10 = ldnt4(&q[10 * 64]), x11 = ldnt4(&q[11 * 64]);
            float4 x12 = ldnt4(&q[12 * 64]), x13 = ldnt4(&q[13 * 64]);
            float4 x14 = ldnt4(&q[14 * 64]), x15 = ldnt4(&q[15 * 64]);
            float4 c0 = x0;  acc4(c0, x1);      // chunk 8h+0 (rows 32h+0..3)
            float4 c1 = x2;  acc4(c1, x3);
            float4 c2 = x4;  acc4(c2, x5);
            float4 c3 = x6;  acc4(c3, x7);
            float4 c4 = x8;  acc4(c4, x9);
            float4 c5 = x10; acc4(c5, x11);
            float4 c6 = x12; acc4(c6, x13);
            float4 c7 = x14; acc4(c7, x15);
            c0 = xor32_add(c0); c1 = xor32_add(c1);   // fold even/odd rows -> chunk sums
            c2 = xor32_add(c2); c3 = xor32_add(c3);
            c4 = xor32_add(c4); c5 = xor32_add(c5);
            c6 = xor32_add(c6); c7 = xor32_add(c7);
            float4 pA, pB;
            acc4(run, c0); pA = run;            // P[8h+0]
            acc4(run, c1); pB = run;            // P[8h+1]
            ((float4*)Pb)[(size_t)(8 * h + 0) * 32 + lane] = hi ? pB : pA;
            acc4(run, c2); pA = run;
            acc4(run, c3); pB = run;
            ((float4*)Pb)[(size_t)(8 * h + 2) * 32 + lane] = hi ? pB : pA;
            acc4(run, c4); pA = run;
            acc4(run, c5); pB = run;
            ((float4*)Pb)[(size_t)(8 * h + 4) * 32 + lane] = hi ? pB : pA;
            acc4(run, c6); pA = run;
            acc4(run, c7); pB = run;
            ((float4*)Pb)[(size_t)(8 * h + 6) * 32 + lane] = hi ? pB : pA;
        }
    } else {                        // pool2: 256 ch, one full row per load, superchunk 32 rows
        const int idx = w - 3072;
        const int b = idx >> 7, sc = idx & 127;
        const float4* p = (const float4*)v2 + ((size_t)b * 4096 + (size_t)sc * 32) * 64 + lane;
        float* Pb = ws + P2_OFF + ((size_t)b * 1024 + (size_t)sc * 8) * 256;
        float4 run = make_float4(0.f, 0.f, 0.f, 0.f);
#pragma unroll
        for (int h = 0; h < 2; h++) {           // 16 rows = 4 chunks; 16 loads in flight
            const float4* q = p + (size_t)(16 * h) * 64;
            float4 r0  = ldnt4(&q[ 0 * 64]), r1  = ldnt4(&q[ 1 * 64]);
            float4 r2  = ldnt4(&q[ 2 * 64]), r3  = ldnt4(&q[ 3 * 64]);
            float4 r4  = ldnt4(&q[ 4 * 64]), r5  = ldnt4(&q[ 5 * 64]);
            float4 r6  = ldnt4(&q[ 6 * 64]), r7  = ldnt4(&q[ 7 * 64]);
            float4 r8  = ldnt4(&q[ 8 * 64]), r9  = ldnt4(&q[ 9 * 64]);
            float4 r10 = ldnt4(&q[10 * 64]), r11 = ldnt4(&q[11 * 64]);
            float4 r12 = ldnt4(&q[12 * 64]), r13 = ldnt4(&q[13 * 64]);
            float4 r14 = ldnt4(&q[14 * 64]), r15 = ldnt4(&q[15 * 64]);
            float4 c0 = r0;  acc4(c0, r1);  acc4(c0, r2);  acc4(c0, r3);
            float4 c1 = r4;  acc4(c1, r5);  acc4(c1, r6);  acc4(c1, r7);
            float4 c2 = r8;  acc4(c2, r9);  acc4(c2, r10); acc4(c2, r11);
            float4 c3 = r12; acc4(c3, r13); acc4(c3, r14); acc4(c3, r15);
            acc4(run, c0);
            ((float4*)Pb)[(size_t)(4 * h + 0) * 64 + lane] = run;
            acc4(run, c1);
            ((float4*)Pb)[(size_t)(4 * h + 1) * 64 + lane] = run;
            acc4(run, c2);
            ((float4*)Pb)[(size_t)(4 * h + 2) * 64 + lane] = run;
            acc4(run, c3);
            ((float4*)Pb)[(size_t)(4 * h + 3) * 64 + lane] = run;
        }
    }
}

// ---------------- pass 2: gather via prefix differences (chunk = 4 rows) ----------------
__global__ __launch_bounds__(256) void gather_kernel(
    const float* __restrict__ v0, const float* __restrict__ v1,
    const float* __restrict__ v2, const float* __restrict__ start,
    const float* __restrict__ dur, const float* __restrict__ ws,
    float* __restrict__ out)
{
    const int wave    = threadIdx.x >> 6;
    const int lane    = threadIdx.x & 63;
    const int lane_lo = lane & 31;
    const int hi      = lane >> 5;
    const int bn      = blockIdx.x * 4 + wave;   // [0, 4096)
    const int b       = bn >> 9;
    const int pool    = blockIdx.y;

    const float st = start[bn];
    const float du = dur[bn];
    float* outbase = out + (size_t)bn * 512;

    if (pool < 2) {
        const float*  v   = (pool == 0) ? v0 : v1;
        const float*  P   = ws + ((pool == 0) ? P0_OFF : P1_OFF);
        const int     T   = (pool == 0) ? 16384 : 8192;
        const int     NCH = T / 4;               // chunks per batch-row
        const float   r   = (pool == 0) ? 1.0f : 0.5f;
        const int s = min((int)floorf(st * r), T - 1);
        const int e = min((int)ceilf((st + du + kEps) * r), T - 1);
        const int cnt = e - s;

        float4 acc = make_float4(0.f, 0.f, 0.f, 0.f);
        if (cnt > 0) {
            const float4* vp = (const float4*)v + (size_t)b * T * 32;
            const float4* Pb = (const float4*)P + (size_t)b * NCH * 32;
            const int cs = (s + 3) >> 2;
            const int ce = e >> 2;
            if (ce > cs) {
                // paired load: lo half = Q-entry (subtract), hi half = P[ce-1]
                const int jq = cs & 15;
                const int cq = jq ? cs - 1 : cs;          // dummy (weight 0) when aligned
                const int ilo = cq * 32 + lane_lo;
                const int ihi = (ce - 1) * 32 + lane_lo;
                float4 x = Pb[(size_t)(hi ? ihi : ilo)];
                const float wq = hi ? 1.f : (jq ? -1.f : 0.f);
                acc4w(acc, x, wq);
                // middle superchunk totals SS[m] = P[16m+15], m in [cs>>4, (ce-1)>>4)
                int m  = cs >> 4;
                const int me = (ce - 1) >> 4;
                for (; m + 2 <= me; m += 2) {             // paired, 2 SS per load
                    const int i0 = (m * 16 + 15) * 32 + lane_lo;
                    const int i1 = ((m + 1) * 16 + 15) * 32 + lane_lo;
                    float4 y = Pb[(size_t)(hi ? i1 : i0)];
                    acc4(acc, y);
                }
                if (m < me) {                             // odd tail SS: lo half only
                    float4 y = Pb[(size_t)((m * 16 + 15) * 32 + lane_lo)];
                    acc4w(acc, y, hi ? 0.f : 1.f);
                }
                // edges: <=3 rows each end, pair-row loads with hi-half masking
                const int fe = cs << 2;
                for (int t = s; t < fe; t += 2) {
                    float4 x2 = vp[(size_t)t * 32 + lane];
                    if (hi == 0 || t + 1 < fe) acc4(acc, x2);
                }
                const int be = ce << 2;
                for (int t = be; t < e; t += 2) {
                    float4 x2 = vp[(size_t)t * 32 + lane];
                    if (hi == 0 || t + 1 < e) acc4(acc, x2);
                }
            } else {
                for (int t = s; t < e; t += 2) {          // short segment (<=7 rows)
                    float4 x2 = vp[(size_t)t * 32 + lane];
                    if (hi == 0 || t + 1 < e) acc4(acc, x2);
                }
            }
        }
        float4 res = make_float4(0.f, 0.f, 0.f, 0.f);
        if (cnt > 0) {
            acc = xor32_add(acc);                         // fold halves (P diff + SS + edges)
            const float inv = 1.0f / (float)cnt;
            res.x = acc.x * inv; res.y = acc.y * inv;
            res.z = acc.z * inv; res.w = acc.w * inv;
        }
        if (hi == 0)
            ((float4*)(outbase + (pool == 0 ? 0 : 128)))[lane_lo] = res;
    } else {
        const int   T   = 4096;
        const int   NCH = T / 4;
        const float r   = 0.25f;
        const int s = min((int)floorf(st * r), T - 1);
        const int e = min((int)ceilf((st + du + kEps) * r), T - 1);
        const int cnt = e - s;

        float4 acc = make_float4(0.f, 0.f, 0.f, 0.f);
        if (cnt > 0) {
            const float4* vp = (const float4*)v2 + (size_t)b * T * 64 + lane;
            const float4* Pb = (const float4*)(ws + P2_OFF) + (size_t)b * NCH * 64 + lane;
            const int cs = (s + 3) >> 2;
            const int ce = e >> 2;
            if (ce > cs) {
                acc = Pb[(size_t)(ce - 1) * 64];          // within-superchunk prefix of ce-1
                const int jq = cs & 7;
                if (jq) sub4(acc, Pb[(size_t)(cs - 1) * 64]);
                int m  = cs >> 3;
                const int me = (ce - 1) >> 3;
                for (; m < me; ++m)                       // middle SS[m] = P[8m+7]
                    acc4(acc, Pb[(size_t)(m * 8 + 7) * 64]);
                for (int t = s; t < (cs << 2); ++t) acc4(acc, vp[(size_t)t * 64]);  // <=3
                for (int t = (ce << 2); t < e; ++t) acc4(acc, vp[(size_t)t * 64]);  // <=3
            } else {
                for (int t = s; t < e; ++t) acc4(acc, vp[(size_t)t * 64]);
            }
        }
        float4 res = make_float4(0.f, 0.f, 0.f, 0.f);
        if (cnt > 0) {
            const float inv = 1.0f / (float)cnt;
            res.x = acc.x * inv; res.y = acc.y * inv;
            res.z = acc.z * inv; res.w = acc.w * inv;
        }
        ((float4*)(outbase + 256))[lane] = res;
    }
}

extern "C" void kernel_launch(void* const* d_in, const int* in_sizes, int n_in,
                              void* d_out, int out_size, void* d_ws, size_t ws_size,
                              hipStream_t stream) {
    const float* v0    = (const float*)d_in[0];
    const float* v1    = (const float*)d_in[1];
    const float* v2    = (const float*)d_in[2];
    const float* start = (const float*)d_in[3];
    const float* dur   = (const float*)d_in[4];
    float*       out   = (float*)d_out;
    float*       ws    = (float*)d_ws;

    // Pass 1: 4096 waves (2048 + 1024 + 1024), 4 waves/block
    prefix_kernel<<<dim3(4096 / 4), 256, 0, stream>>>(v0, v1, v2, ws);
    // Pass 2: one wave per (bn, pool)
    gather_kernel<<<dim3(kB * kN / 4, 3), 256, 0, stream>>>(v0, v1, v2, start, dur, ws, out);
}

// Round 10
// 165.012 us; speedup vs baseline: 1.0308x; 1.0308x over previous
//
#include <hip/hip_runtime.h>

// InformPooling, two-pass scheme, chunk=4 rows with within-superchunk prefix sums.
//   value0 [8,16384,128] r=1.0 ; value1 [8,8192,128] r=0.5 ; value2 [8,4096,256] r=0.25
//   start/duration [8,512]; out [8,512,512] f32 (channels concat 128|128|256).
//
// Wall decomposition (R6-R9): ~80us harness ws re-poison fills (2x256MiB @6.6TB/s,
//   uncontrollable) + ~25-30us launch gaps + prefix (~35) + gather (~22).
// History: R4 nt-loads cut prefix 47-><40 (wall-neutral: gather edges went cold);
//   R7 chunk 8->4 cut edges to <=3 rows/end -> wall 166.5 (session best).
//   R9 16-deep load batching REGRESSED (170.1) -> this is the exact R7 revert.
// Pass 1 (prefix): nt-load v (keeps LLC clean). Wave owns a superchunk (pools0/1:
//   64 rows = 16 chunks of 4; pool2: 32 rows = 8 chunks), writes inclusive prefix of
//   chunk sums into P, 8 loads in flight per batch. Stores inside the batch loop
//   (R3 spill lesson). P0 [8][4096][128], P1 [8][2048][128], P2 [8][1024][256]
//   = 33.6 MB, temporal.
// Pass 2 (gather): interior [cs,ce) = P[ce-1] - (cs%SCH ? P[cs-1] : 0) + middle SS
//   (SS[m]=P[m*SCH+SCH-1]); edges <=3 rows from v each end.

constexpr int   kB   = 8;
constexpr int   kN   = 512;
constexpr float kEps = 1e-3f;

// float offsets into ws
constexpr size_t P0_OFF = 0;                                 // [8][4096][128]
constexpr size_t P1_OFF = (size_t)8 * 4096 * 128;            // [8][2048][128]
constexpr size_t P2_OFF = P1_OFF + (size_t)8 * 2048 * 128;   // [8][1024][256]

typedef float f32x4 __attribute__((ext_vector_type(4)));

__device__ __forceinline__ float4 ldnt4(const float4* p) {
    f32x4 v = __builtin_nontemporal_load((const f32x4*)p);
    return make_float4(v.x, v.y, v.z, v.w);
}

__device__ __forceinline__ void acc4(float4& a, const float4 x) {
    a.x += x.x; a.y += x.y; a.z += x.z; a.w += x.w;
}
__device__ __forceinline__ void acc4w(float4& a, const float4 x, float w) {
    a.x = fmaf(w, x.x, a.x); a.y = fmaf(w, x.y, a.y);
    a.z = fmaf(w, x.z, a.z); a.w = fmaf(w, x.w, a.w);
}
__device__ __forceinline__ void sub4(float4& a, const float4 x) {
    a.x -= x.x; a.y -= x.y; a.z -= x.z; a.w -= x.w;
}
__device__ __forceinline__ float4 xor32_add(float4 a) {
    a.x += __shfl_xor(a.x, 32);
    a.y += __shfl_xor(a.y, 32);
    a.z += __shfl_xor(a.z, 32);
    a.w += __shfl_xor(a.w, 32);
    return a;
}

// ---------------- pass 1: superchunk prefix sums (chunk = 4 rows) ----------------
// units: pool0 = 2048 (8b x 256 sc of 64 rows), pool1 = 1024 (8b x 128),
//        pool2 = 1024 (8b x 128 sc of 32 rows).  4096 waves total.
__global__ __launch_bounds__(256) void prefix_kernel(
    const float* __restrict__ v0, const float* __restrict__ v1,
    const float* __restrict__ v2, float* __restrict__ ws)
{
    const int w    = (blockIdx.x * 256 + threadIdx.x) >> 6;
    const int lane = threadIdx.x & 63;
    const int hi   = lane >> 5;

    if (w < 3072) {                 // pools 0/1: pair-row layout (lane<32 even row, lane>=32 odd)
        const float* v;  float* Pb;  int T;
        int b, sc;
        if (w < 2048) { b = w >> 8;  sc = w & 255;  v = v0; T = 16384;
                        Pb = ws + P0_OFF + ((size_t)b * 4096 + (size_t)sc * 16) * 128; }
        else { const int idx = w - 2048; b = idx >> 7; sc = idx & 127; v = v1; T = 8192;
               Pb = ws + P1_OFF + ((size_t)b * 2048 + (size_t)sc * 16) * 128; }

        const float4* p = (const float4*)v + ((size_t)b * T + (size_t)sc * 64) * 32 + lane;
        float4 run = make_float4(0.f, 0.f, 0.f, 0.f);
#pragma unroll
        for (int k = 0; k < 4; k++) {           // 16 rows = 4 chunks; 8 pair-loads in flight
            float4 x0 = ldnt4(&p[(8 * k + 0) * 64]), x1 = ldnt4(&p[(8 * k + 1) * 64]);
            float4 x2 = ldnt4(&p[(8 * k + 2) * 64]), x3 = ldnt4(&p[(8 * k + 3) * 64]);
            float4 x4 = ldnt4(&p[(8 * k + 4) * 64]), x5 = ldnt4(&p[(8 * k + 5) * 64]);
            float4 x6 = ldnt4(&p[(8 * k + 6) * 64]), x7 = ldnt4(&p[(8 * k + 7) * 64]);
            float4 c0 = x0; acc4(c0, x1);        // chunk 4k   (rows 16k..16k+3)
            float4 c1 = x2; acc4(c1, x3);        // chunk 4k+1
            float4 c2 = x4; acc4(c2, x5);        // chunk 4k+2
            float4 c3 = x6; acc4(c3, x7);        // chunk 4k+3
            c0 = xor32_add(c0); c1 = xor32_add(c1);   // chunk sums replicated in both halves
            c2 = xor32_add(c2); c3 = xor32_add(c3);
            acc4(run, c0); float4 pA = run;      // P[4k]
            acc4(run, c1); float4 pB = run;      // P[4k+1]
            float4 valA = hi ? pB : pA;          // paired store: lo=P[4k], hi=P[4k+1]
            ((float4*)Pb)[(size_t)(4 * k) * 32 + lane] = valA;
            acc4(run, c2); float4 pC = run;      // P[4k+2]
            acc4(run, c3);                       // P[4k+3] (== run)
            float4 valB = hi ? run : pC;
            ((float4*)Pb)[(size_t)(4 * k + 2) * 32 + lane] = valB;
        }
    } else {                        // pool2: 256 ch, one row per load, superchunk 32 rows
        const int idx = w - 3072;
        const int b = idx >> 7, sc = idx & 127;
        const float4* p = (const float4*)v2 + ((size_t)b * 4096 + (size_t)sc * 32) * 64 + lane;
        float* Pb = ws + P2_OFF + ((size_t)b * 1024 + (size_t)sc * 8) * 256;
        float4 run = make_float4(0.f, 0.f, 0.f, 0.f);
#pragma unroll
        for (int k = 0; k < 4; k++) {           // 8 rows = 2 chunks; 8 loads in flight
            float4 r0 = ldnt4(&p[(8 * k + 0) * 64]), r1 = ldnt4(&p[(8 * k + 1) * 64]);
            float4 r2 = ldnt4(&p[(8 * k + 2) * 64]), r3 = ldnt4(&p[(8 * k + 3) * 64]);
            float4 r4 = ldnt4(&p[(8 * k + 4) * 64]), r5 = ldnt4(&p[(8 * k + 5) * 64]);
            float4 r6 = ldnt4(&p[(8 * k + 6) * 64]), r7 = ldnt4(&p[(8 * k + 7) * 64]);
            float4 a0 = r0; acc4(a0, r1); acc4(a0, r2); acc4(a0, r3);
            float4 a1 = r4; acc4(a1, r5); acc4(a1, r6); acc4(a1, r7);
            acc4(run, a0);
            ((float4*)Pb)[(size_t)(2 * k) * 64 + lane] = run;        // P[2k]
            acc4(run, a1);
            ((float4*)Pb)[(size_t)(2 * k + 1) * 64 + lane] = run;    // P[2k+1]
        }
    }
}

// ---------------- pass 2: gather via prefix differences (chunk = 4 rows) ----------------
__global__ __launch_bounds__(256) void gather_kernel(
    const float* __restrict__ v0, const float* __restrict__ v1,
    const float* __restrict__ v2, const float* __restrict__ start,
    const float* __restrict__ dur, const float* __restrict__ ws,
    float* __restrict__ out)
{
    const int wave    = threadIdx.x >> 6;
    const int lane    = threadIdx.x & 63;
    const int lane_lo = lane & 31;
    const int hi      = lane >> 5;
    const int bn      = blockIdx.x * 4 + wave;   // [0, 4096)
    const int b       = bn >> 9;
    const int pool    = blockIdx.y;

    const float st = start[bn];
    const float du = dur[bn];
    float* outbase = out + (size_t)bn * 512;

    if (pool < 2) {
        const float*  v   = (pool == 0) ? v0 : v1;
        const float*  P   = ws + ((pool == 0) ? P0_OFF : P1_OFF);
        const int     T   = (pool == 0) ? 16384 : 8192;
        const int     NCH = T / 4;               // chunks per batch-row
        const float   r   = (pool == 0) ? 1.0f : 0.5f;
        const int s = min((int)floorf(st * r), T - 1);
        const int e = min((int)ceilf((st + du + kEps) * r), T - 1);
        const int cnt = e - s;

        float4 acc = make_float4(0.f, 0.f, 0.f, 0.f);
        if (cnt > 0) {
            const float4* vp = (const float4*)v + (size_t)b * T * 32;
            const float4* Pb = (const float4*)P + (size_t)b * NCH * 32;
            const int cs = (s + 3) >> 2;
            const int ce = e >> 2;
            if (ce > cs) {
                // paired load: lo half = Q-entry (subtract), hi half = P[ce-1]
                const int jq = cs & 15;
                const int cq = jq ? cs - 1 : cs;          // dummy (weight 0) when aligned
                const int ilo = cq * 32 + lane_lo;
                const int ihi = (ce - 1) * 32 + lane_lo;
                float4 x = Pb[(size_t)(hi ? ihi : ilo)];
                const float wq = hi ? 1.f : (jq ? -1.f : 0.f);
                acc4w(acc, x, wq);
                // middle superchunk totals SS[m] = P[16m+15], m in [cs>>4, (ce-1)>>4)
                int m  = cs >> 4;
                const int me = (ce - 1) >> 4;
                for (; m + 2 <= me; m += 2) {             // paired, 2 SS per load
                    const int i0 = (m * 16 + 15) * 32 + lane_lo;
                    const int i1 = ((m + 1) * 16 + 15) * 32 + lane_lo;
                    float4 y = Pb[(size_t)(hi ? i1 : i0)];
                    acc4(acc, y);
                }
                if (m < me) {                             // odd tail SS: lo half only
                    float4 y = Pb[(size_t)((m * 16 + 15) * 32 + lane_lo)];
                    acc4w(acc, y, hi ? 0.f : 1.f);
                }
                // edges: <=3 rows each end, pair-row loads with hi-half masking
                const int fe = cs << 2;
                for (int t = s; t < fe; t += 2) {
                    float4 x2 = vp[(size_t)t * 32 + lane];
                    if (hi == 0 || t + 1 < fe) acc4(acc, x2);
                }
                const int be = ce << 2;
                for (int t = be; t < e; t += 2) {
                    float4 x2 = vp[(size_t)t * 32 + lane];
                    if (hi == 0 || t + 1 < e) acc4(acc, x2);
                }
            } else {
                for (int t = s; t < e; t += 2) {          // short segment (<=7 rows)
                    float4 x2 = vp[(size_t)t * 32 + lane];
                    if (hi == 0 || t + 1 < e) acc4(acc, x2);
                }
            }
        }
        float4 res = make_float4(0.f, 0.f, 0.f, 0.f);
        if (cnt > 0) {
            acc = xor32_add(acc);                         // fold halves (P diff + SS + edges)
            const float inv = 1.0f / (float)cnt;
            res.x = acc.x * inv; res.y = acc.y * inv;
            res.z = acc.z * inv; res.w = acc.w * inv;
        }
        if (hi == 0)
            ((float4*)(outbase + (pool == 0 ? 0 : 128)))[lane_lo] = res;
    } else {
        const int   T   = 4096;
        const int   NCH = T / 4;
        const float r   = 0.25f;
        const int s = min((int)floorf(st * r), T - 1);
        const int e = min((int)ceilf((st + du + kEps) * r), T - 1);
        const int cnt = e - s;

        float4 acc = make_float4(0.f, 0.f, 0.f, 0.f);
        if (cnt > 0) {
            const float4* vp = (const float4*)v2 + (size_t)b * T * 64 + lane;
            const float4* Pb = (const float4*)(ws + P2_OFF) + (size_t)b * NCH * 64 + lane;
            const int cs = (s + 3) >> 2;
            const int ce = e >> 2;
            if (ce > cs) {
                acc = Pb[(size_t)(ce - 1) * 64];          // within-superchunk prefix of ce-1
                const int jq = cs & 7;
                if (jq) sub4(acc, Pb[(size_t)(cs - 1) * 64]);
                int m  = cs >> 3;
                const int me = (ce - 1) >> 3;
                for (; m < me; ++m)                       // middle SS[m] = P[8m+7]
                    acc4(acc, Pb[(size_t)(m * 8 + 7) * 64]);
                for (int t = s; t < (cs << 2); ++t) acc4(acc, vp[(size_t)t * 64]);  // <=3
                for (int t = (ce << 2); t < e; ++t) acc4(acc, vp[(size_t)t * 64]);  // <=3
            } else {
                for (int t = s; t < e; ++t) acc4(acc, vp[(size_t)t * 64]);
            }
        }
        float4 res = make_float4(0.f, 0.f, 0.f, 0.f);
        if (cnt > 0) {
            const float inv = 1.0f / (float)cnt;
            res.x = acc.x * inv; res.y = acc.y * inv;
            res.z = acc.z * inv; res.w = acc.w * inv;
        }
        ((float4*)(outbase + 256))[lane] = res;
    }
}

extern "C" void kernel_launch(void* const* d_in, const int* in_sizes, int n_in,
                              void* d_out, int out_size, void* d_ws, size_t ws_size,
                              hipStream_t stream) {
    const float* v0    = (const float*)d_in[0];
    const float* v1    = (const float*)d_in[1];
    const float* v2    = (const float*)d_in[2];
    const float* start = (const float*)d_in[3];
    const float* dur   = (const float*)d_in[4];
    float*       out   = (float*)d_out;
    float*       ws    = (float*)d_ws;

    // Pass 1: 4096 waves (2048 + 1024 + 1024), 4 waves/block
    prefix_kernel<<<dim3(4096 / 4), 256, 0, stream>>>(v0, v1, v2, ws);
    // Pass 2: one wave per (bn, pool)
    gather_kernel<<<dim3(kB * kN / 4, 3), 256, 0, stream>>>(v0, v1, v2, start, dur, ws, out);
}